// Round 14
// baseline (218.026 us; speedup 1.0000x reference)
//
#include <hip/hip_runtime.h>
#include <hip/hip_bf16.h>

// NT-Xent loss: B=4096, D=128, TEMP=0.5, N2=8192.
// loss = mean_i [ log sum_{j!=i} exp(2*sim_ij) - 2*pos_i ]
// sim = zn zn^T (bf16 MFMA), pos_i = fp32 cosine(z_i, z_{i^B}).
// Self-diagonal handled by diag[i] = -exp2(sii_scaled) added in the tail.
//
// R14: KILL THE ATOMICS. R5-R13 falsified occupancy, barriers, staging,
// wave-coupling, and work-volume (R12: half work = same time) as the
// ~34us sim bottleneck. The one invariant never varied: 262k device-scope
// atomicAdds onto 8192 contiguous floats (512 lines -> ~512 serialized
// RMWs/line at the coherent point). Replace with contention-free plain
// stores to part[cs][row] (1 MB), reduced in a fused tail (R7-proven
// panel-counter pattern, atomic reads for cross-XCD visibility). Also
// deletes the finalize dispatch (+1 gap). Sim body = R11 verbatim.

#define BB 4096
#define N2 8192
#define DD 128
#define CSPLIT 32          // column splits (grid.x)
#define CW (N2 / CSPLIT)   // 256 cols per block
#define TW 64              // cols staged per round (4 col-tiles, 16 KB)
#define NRD (CW / TW)      // 4 rounds
#define NPANEL 32          // row panels (grid.y)
#define NBLOCKS (CSPLIT * NPANEL)

// sqrt(2*log2(e)): zn scaled by this => A.B = 2*log2(e)*sim, so
// exp(2*sim) = exp2(A.B) directly.
#define SCALE 1.69864360f

#if __has_builtin(__builtin_amdgcn_exp2f)
#define EXP2F(x) __builtin_amdgcn_exp2f(x)
#else
#define EXP2F(x) __expf((x) * 0.6931471805599453f)
#endif

using bf16 = __hip_bfloat16;
typedef __attribute__((ext_vector_type(8))) short short8;   // MFMA A/B frag
typedef __attribute__((ext_vector_type(4))) float float4v;  // MFMA C/D frag

// ---------------- Kernel 1: per-pair normalize, scale, cast bf16 ----------
__global__ __launch_bounds__(256) void ntx_norm_kernel(
    const float* __restrict__ zi, const float* __restrict__ zj,
    bf16* __restrict__ zn, float* __restrict__ diag, float* __restrict__ pos,
    float* __restrict__ accum, unsigned int* __restrict__ panelCnt,
    unsigned int* __restrict__ globalCnt) {
  const int wave = threadIdx.x >> 6;
  const int lane = threadIdx.x & 63;
  // zero the sim kernel's completion counters (stream order makes this
  // visible before any sim block runs; ws is re-poisoned every replay)
  if (blockIdx.x == 0 && threadIdx.x < 34) {
    if (threadIdx.x < 32) panelCnt[threadIdx.x] = 0u;
    else if (threadIdx.x == 32) *globalCnt = 0u;
    else *accum = 0.0f;
  }
  const int pair = blockIdx.x * 4 + wave;   // 1024 blocks, 4 pairs/block
  float2 v = ((const float2*)(zi + (size_t)pair * DD))[lane];
  float2 w = ((const float2*)(zj + (size_t)pair * DD))[lane];
  float s1 = v.x * v.x + v.y * v.y;
  float s2 = w.x * w.x + w.y * w.y;
  float s3 = v.x * w.x + v.y * w.y;
  #pragma unroll
  for (int o = 32; o > 0; o >>= 1) {
    s1 += __shfl_xor(s1, o);
    s2 += __shfl_xor(s2, o);
    s3 += __shfl_xor(s3, o);
  }
  float nv = fmaxf(sqrtf(s1), 1e-8f);
  float nw = fmaxf(sqrtf(s2), 1e-8f);
  float rv = SCALE / nv, rw = SCALE / nw;   // scale folded into zn
  bf16 bx = __float2bfloat16(v.x * rv);
  bf16 by = __float2bfloat16(v.y * rv);
  bf16 cx = __float2bfloat16(w.x * rw);
  bf16 cy = __float2bfloat16(w.y * rw);
  __hip_bfloat162 h2; h2.x = bx; h2.y = by;
  __hip_bfloat162 g2; g2.x = cx; g2.y = cy;
  ((__hip_bfloat162*)(zn + (size_t)pair * DD))[lane] = h2;
  ((__hip_bfloat162*)(zn + (size_t)(pair + BB) * DD))[lane] = g2;
  // self-dot in the SAME scaled bf16 precision the MFMA will see
  float fx = __bfloat162float(bx), fy = __bfloat162float(by);
  float gx = __bfloat162float(cx), gy = __bfloat162float(cy);
  float sii = fx * fx + fy * fy;            // = 2log2e * sim_ii (scaled)
  float sjj = gx * gx + gy * gy;
  #pragma unroll
  for (int o = 32; o > 0; o >>= 1) {
    sii += __shfl_xor(sii, o);
    sjj += __shfl_xor(sjj, o);
  }
  if (lane == 0) {
    float c = s3 / (nv * nw);               // fp32 positive-pair cosine
    diag[pair]      = -EXP2F(sii);          // cancels diagonal term (tail)
    diag[pair + BB] = -EXP2F(sjj);
    pos[pair]      = c;
    pos[pair + BB] = c;
  }
}

// ---------------- Kernel 2: fused sim + sum-exp + finalize -----------------
// grid (CSPLIT=32, NPANEL=32). Block = 4 waves; wave owns 64 rows, block
// 256 rows x 256 cols. R11 body: reg-staged B (pre-swizzled src, loads
// EARLY), double-buffered LDS, 1 barrier/round, pinned A frags.
// Row-sum partials -> PLAIN stores to part[cs][row] (no atomics).
// Tail: panel-last block sums 32 partials + diag, log - 2 pos, one accum
// atomic; global-last block writes out.
__global__ __launch_bounds__(256) void ntx_sim_kernel(
    const bf16* __restrict__ zn, float* __restrict__ part,
    const float* __restrict__ diag, const float* __restrict__ pos,
    float* __restrict__ accum, unsigned int* __restrict__ panelCnt,
    unsigned int* __restrict__ globalCnt, float* __restrict__ out) {
  const int tid  = threadIdx.x;
  const int wave = tid >> 6;
  const int lane = tid & 63;
  const int quad = lane >> 4;
  const int l15  = lane & 15;
  const char* zb  = (const char*)zn;
  const short* zs = (const short*)zn;

  __shared__ float4 lds[2][TW * 16];   // 2 x 16 KB double buffer
  __shared__ float psm[4];
  __shared__ unsigned int lastPanel;

  const int rowBase  = blockIdx.y * 256 + wave * 64;
  const int colBase0 = blockIdx.x * CW;

  // Staging map: 1024 chunks of 16B per round; thread owns chunks
  // tid + q*256. LDS[g][slot] holds global chunk (slot ^ (g&7)) of
  // col-row g -> swizzled ds_read_b128 is uniform 8 dwords/bank.
  const int g0 = tid >> 4;
  const int sw = ((tid & 15) ^ (g0 & 7)) << 4;
  const char* srcb = zb + (size_t)(colBase0 + g0) * 256 + sw;

  // prologue: stage round 0
  float4 p0 = *(const float4*)(srcb);
  float4 p1 = *(const float4*)(srcb + 4096);
  float4 p2 = *(const float4*)(srcb + 8192);
  float4 p3 = *(const float4*)(srcb + 12288);

  // A fragments: 4 row-tiles x 4 K-chunks (64 VGPRs) — full-line reads
  short8 a[4][4];
  #pragma unroll
  for (int t = 0; t < 4; t++) {
    const short* ap = zs + (size_t)(rowBase + t * 16 + l15) * DD + quad * 8;
    #pragma unroll
    for (int c = 0; c < 4; c++) a[t][c] = *(const short8*)(ap + c * 32);
  }
  // keep A resident (R10 pathology guard)
  asm volatile("" : "+v"(a[0][0]), "+v"(a[0][1]), "+v"(a[0][2]), "+v"(a[0][3]),
                    "+v"(a[1][0]), "+v"(a[1][1]), "+v"(a[1][2]), "+v"(a[1][3]),
                    "+v"(a[2][0]), "+v"(a[2][1]), "+v"(a[2][2]), "+v"(a[2][3]),
                    "+v"(a[3][0]), "+v"(a[3][1]), "+v"(a[3][2]), "+v"(a[3][3]));

  float rs[4][4];
  #pragma unroll
  for (int t = 0; t < 4; t++)
    #pragma unroll
    for (int r = 0; r < 4; r++) rs[t][r] = 0.0f;

  lds[0][tid] = p0;
  lds[0][tid + 256] = p1;
  lds[0][tid + 512] = p2;
  lds[0][tid + 768] = p3;
  __syncthreads();

  int cur = 0;
  #pragma unroll 1
  for (int rd = 0; rd < NRD; rd++) {
    // issue next round's loads EARLY — latency hides under this round
    float4 t0, t1, t2, t3;
    const bool pf = (rd + 1 < NRD);
    if (pf) {
      const char* sb = srcb + (size_t)(rd + 1) * (TW * 256);
      t0 = *(const float4*)(sb);
      t1 = *(const float4*)(sb + 4096);
      t2 = *(const float4*)(sb + 8192);
      t3 = *(const float4*)(sb + 12288);
    }

    const char* lb = (const char*)&lds[cur][0];
    #pragma unroll
    for (int k = 0; k < 4; k++) {           // 4 col-tiles per round
      short8 b[4];
      #pragma unroll
      for (int c = 0; c < 4; c++) {
        const int off = k * 4096 + l15 * 256 +
                        ((((c * 4 + quad) ^ (l15 & 7))) << 4);
        b[c] = *(const short8*)(lb + off);
      }
      #pragma unroll
      for (int t = 0; t < 4; t++) {
        float4v acc = {0.f, 0.f, 0.f, 0.f};
        acc = __builtin_amdgcn_mfma_f32_16x16x32_bf16(a[t][0], b[0], acc, 0, 0, 0);
        acc = __builtin_amdgcn_mfma_f32_16x16x32_bf16(a[t][1], b[1], acc, 0, 0, 0);
        acc = __builtin_amdgcn_mfma_f32_16x16x32_bf16(a[t][2], b[2], acc, 0, 0, 0);
        acc = __builtin_amdgcn_mfma_f32_16x16x32_bf16(a[t][3], b[3], acc, 0, 0, 0);
        // C/D: col = l15, row = quad*4 + r [m89/m91]; acc = 2log2e*sim.
        #pragma unroll
        for (int r = 0; r < 4; r++) rs[t][r] += EXP2F(acc[r]);
      }
    }

    if (pf) {
      lds[cur ^ 1][tid] = t0;
      lds[cur ^ 1][tid + 256] = t1;
      lds[cur ^ 1][tid + 512] = t2;
      lds[cur ^ 1][tid + 768] = t3;
      __syncthreads();
      cur ^= 1;
    }
  }

  // partial row-sums -> PLAIN stores (no contention, no RMW)
  float* myPart = part + (size_t)blockIdx.x * N2;
  #pragma unroll
  for (int t = 0; t < 4; t++) {
    #pragma unroll
    for (int r = 0; r < 4; r++) {
      float s = rs[t][r];
      s += __shfl_xor(s, 1);
      s += __shfl_xor(s, 2);
      s += __shfl_xor(s, 4);
      s += __shfl_xor(s, 8);
      if (l15 == 0)
        myPart[rowBase + t * 16 + quad * 4 + r] = s;
    }
  }

  // ---- fused finalize (R7-proven pattern) ----
  __threadfence();                       // release partial stores
  if (tid == 0) lastPanel = atomicAdd(&panelCnt[blockIdx.y], 1u);
  __syncthreads();
  if (lastPanel == CSPLIT - 1) {
    // last block of this 256-row panel: reduce its rows
    const int r = blockIdx.y * 256 + tid;
    // atomic reads: coherent point, safe vs other-XCD plain stores
    float s0 = diag[r];   // written by norm kernel (prior dispatch)
    float s1 = 0.f, s2 = 0.f, s3 = 0.f;
    #pragma unroll
    for (int cs = 0; cs < CSPLIT; cs += 4) {
      s0 += atomicAdd(&part[(size_t)(cs + 0) * N2 + r], 0.0f);
      s1 += atomicAdd(&part[(size_t)(cs + 1) * N2 + r], 0.0f);
      s2 += atomicAdd(&part[(size_t)(cs + 2) * N2 + r], 0.0f);
      s3 += atomicAdd(&part[(size_t)(cs + 3) * N2 + r], 0.0f);
    }
    float v = __logf((s0 + s1) + (s2 + s3)) - 2.0f * pos[r];
    #pragma unroll
    for (int o = 32; o > 0; o >>= 1) v += __shfl_xor(v, o);
    if (lane == 0) psm[wave] = v;
    __syncthreads();
    if (tid == 0)
      atomicAdd(accum, psm[0] + psm[1] + psm[2] + psm[3]);
  }
  __threadfence();
  if (tid == 0) {
    unsigned int g = atomicAdd(globalCnt, 1u);
    if (g == NBLOCKS - 1)                // last block overall
      out[0] = atomicAdd(accum, 0.0f) / (float)N2;
  }
}

extern "C" void kernel_launch(void* const* d_in, const int* in_sizes, int n_in,
                              void* d_out, int out_size, void* d_ws, size_t ws_size,
                              hipStream_t stream) {
  const float* zi = (const float*)d_in[0];
  const float* zj = (const float*)d_in[1];
  float* out = (float*)d_out;

  char* ws = (char*)d_ws;
  bf16* zn = (bf16*)ws;                                   // 2 MB
  float* part = (float*)(ws + (size_t)N2 * DD * 2);       // 32*8192*4 = 1 MB
  float* diag = part + (size_t)CSPLIT * N2;               // 32 KB
  float* pos  = diag + N2;                                // 32 KB
  float* accum = pos + N2;                                // 4 B
  unsigned int* panelCnt = (unsigned int*)(accum + 1);    // 128 B
  unsigned int* globalCnt = panelCnt + NPANEL;            // 4 B

  ntx_norm_kernel<<<BB / 4, 256, 0, stream>>>(zi, zj, zn, diag, pos,
                                              accum, panelCnt, globalCnt);
  dim3 grid(CSPLIT, NPANEL);
  ntx_sim_kernel<<<grid, 256, 0, stream>>>(zn, part, diag, pos, accum,
                                           panelCnt, globalCnt, out);
}

// Round 15
// 88.987 us; speedup vs baseline: 2.4501x; 2.4501x over previous
//
#include <hip/hip_runtime.h>
#include <hip/hip_bf16.h>

// NT-Xent loss: B=4096, D=128, TEMP=0.5, N2=8192.
// loss = mean_i [ log sum_{j!=i} exp(2*sim_ij) - 2*pos_i ]
// sim = zn zn^T (bf16 MFMA), pos_i = fp32 cosine(z_i, z_{i^B}).
// Self-diagonal handled by rowsum init = -exp2(sii_scaled).
//
// R15: PRE-PACKED FRAGMENTS. R14's fused tail (device fences + counter +
// atomic-read reduction) cost ~135us -> reverted; 3-kernel R11 shape.
// New theory: the one invariant across ALL variants is the fragment
// reformat at consume time (256B-strided lane addressing, scattered
// global or LDS stage+swizzle+barrier). Fix at PRODUCE time: norm kernel
// emits zn directly in MFMA fragment order via 8 shfls + one 16B store
// per writer lane -> znP[tile][chunk][lane] (2MB). Sim then loads BOTH
// A and B fragments as base + lane*16: perfectly coalesced, L2-resident,
// ZERO LDS / barriers / swizzle / drains. Inner loop = R0's proven
// bn-prefetch shape. VGPR ~125, no LDS -> occupancy VGPR-bound only.

#define BB 4096
#define N2 8192
#define DD 128
#define CSPLIT 32          // column splits (grid.x)
#define CW (N2 / CSPLIT)   // 256 cols per block
#define NCT (CW / 16)      // 16 col-tiles per block

// sqrt(2*log2(e)): zn scaled by this => A.B = 2*log2(e)*sim, so
// exp(2*sim) = exp2(A.B) directly.
#define SCALE 1.69864360f

#if __has_builtin(__builtin_amdgcn_exp2f)
#define EXP2F(x) __builtin_amdgcn_exp2f(x)
#else
#define EXP2F(x) __expf((x) * 0.6931471805599453f)
#endif

using bf16 = __hip_bfloat16;
typedef __attribute__((ext_vector_type(8))) short short8;   // MFMA A/B frag
typedef __attribute__((ext_vector_type(4))) float float4v;  // MFMA C/D frag

// Packed layout: tile t (16 rows of zn), chunk c (K-chunk of 32):
//   znP + (t*4 + c)*1024 + lane*16  holds  zn[t*16 + (lane&15)]
//                                          [c*32 + (lane>>4)*8 .. +7]
// i.e. exactly the short8 MFMA A/B fragment each lane needs.

// ---------------- Kernel 1: normalize + pack fragments ---------------------
__global__ __launch_bounds__(256) void ntx_norm_kernel(
    const float* __restrict__ zi, const float* __restrict__ zj,
    char* __restrict__ znP, float* __restrict__ rowsum,
    float* __restrict__ pos) {
  const int wave = threadIdx.x >> 6;
  const int lane = threadIdx.x & 63;
  const int pair = blockIdx.x * 4 + wave;   // 1024 blocks, 4 pairs/block
  float2 v = ((const float2*)(zi + (size_t)pair * DD))[lane];
  float2 w = ((const float2*)(zj + (size_t)pair * DD))[lane];
  float s1 = v.x * v.x + v.y * v.y;
  float s2 = w.x * w.x + w.y * w.y;
  float s3 = v.x * w.x + v.y * w.y;
  #pragma unroll
  for (int o = 32; o > 0; o >>= 1) {
    s1 += __shfl_xor(s1, o);
    s2 += __shfl_xor(s2, o);
    s3 += __shfl_xor(s3, o);
  }
  float nv = fmaxf(sqrtf(s1), 1e-8f);
  float nw = fmaxf(sqrtf(s2), 1e-8f);
  float rv = SCALE / nv, rw = SCALE / nw;   // scale folded into zn
  bf16 bx = __float2bfloat16(v.x * rv);
  bf16 by = __float2bfloat16(v.y * rv);
  bf16 cx = __float2bfloat16(w.x * rw);
  bf16 cy = __float2bfloat16(w.y * rw);
  __hip_bfloat162 h2; h2.x = bx; h2.y = by;   // elems 2*lane, 2*lane+1 (row pair)
  __hip_bfloat162 g2; g2.x = cx; g2.y = cy;   // same, row pair+BB
  unsigned hu = *(unsigned*)&h2;
  unsigned gu = *(unsigned*)&g2;

  // Pack: writer lane i (0..15) of each half emits elems 8i..8i+7 of its
  // row as one 16B chunk (c = i>>2, quad = i&3). Source u32 m lives in
  // lane 4i+m. All 64 lanes run the shfls (defined behavior).
  const int i = lane & 15;
  unsigned h0 = __shfl(hu, 4 * i + 0), g0 = __shfl(gu, 4 * i + 0);
  unsigned h1 = __shfl(hu, 4 * i + 1), g1 = __shfl(gu, 4 * i + 1);
  unsigned h2u = __shfl(hu, 4 * i + 2), g2u = __shfl(gu, 4 * i + 2);
  unsigned h3 = __shfl(hu, 4 * i + 3), g3 = __shfl(gu, 4 * i + 3);
  if (lane < 32) {
    const int r = (lane < 16) ? pair : (pair + BB);
    uint4 val;
    val.x = (lane < 16) ? h0 : g0;
    val.y = (lane < 16) ? h1 : g1;
    val.z = (lane < 16) ? h2u : g2u;
    val.w = (lane < 16) ? h3 : g3;
    // dest: tile r>>4, chunk i>>2, lane slot (i&3)*16 + (r&15)
    char* dst = znP + (((size_t)(r >> 4) * 4 + (i >> 2)) << 10) +
                ((((i & 3) << 4) + (r & 15)) << 4);
    *(uint4*)dst = val;
  }

  // self-dot in the SAME scaled bf16 precision the MFMA will see
  float fx = __bfloat162float(bx), fy = __bfloat162float(by);
  float gx = __bfloat162float(cx), gy = __bfloat162float(cy);
  float sii = fx * fx + fy * fy;            // = 2log2e * sim_ii (scaled)
  float sjj = gx * gx + gy * gy;
  #pragma unroll
  for (int o = 32; o > 0; o >>= 1) {
    sii += __shfl_xor(sii, o);
    sjj += __shfl_xor(sjj, o);
  }
  if (lane == 0) {
    float c = s3 / (nv * nw);               // fp32 positive-pair cosine
    rowsum[pair]      = -EXP2F(sii);        // cancels diagonal term
    rowsum[pair + BB] = -EXP2F(sjj);
    pos[pair]      = c;
    pos[pair + BB] = c;
  }
}

// ---------------- Kernel 2: fused sim + sum-exp ----------------------------
// grid (32, 32). Block 256 = 4 waves; wave owns 64 rows (4 row-tiles),
// block owns 256 rows x 256 cols. All fragment loads coalesced from znP
// (base + lane*16). No LDS, no barriers. R0-style bn prefetch.
__global__ __launch_bounds__(256) void ntx_sim_kernel(
    const char* __restrict__ znP, float* __restrict__ rowsum) {
  const int tid  = threadIdx.x;
  const int wave = tid >> 6;
  const int lane = tid & 63;
  const int quad = lane >> 4;
  const int l15  = lane & 15;

  const int rowBase = blockIdx.y * 256 + wave * 64;
  const int tile0   = blockIdx.x * NCT;      // first col-tile of this block

  // A fragments: 4 row-tiles x 4 K-chunks — coalesced packed loads
  const int art = (rowBase >> 4);            // first row-tile index
  short8 a[4][4];
  #pragma unroll
  for (int t = 0; t < 4; t++)
    #pragma unroll
    for (int c = 0; c < 4; c++)
      a[t][c] = *(const short8*)(znP + (((size_t)(art + t) * 4 + c) << 10) +
                                 lane * 16);
  // keep A resident (R10 pathology guard)
  asm volatile("" : "+v"(a[0][0]), "+v"(a[0][1]), "+v"(a[0][2]), "+v"(a[0][3]),
                    "+v"(a[1][0]), "+v"(a[1][1]), "+v"(a[1][2]), "+v"(a[1][3]),
                    "+v"(a[2][0]), "+v"(a[2][1]), "+v"(a[2][2]), "+v"(a[2][3]),
                    "+v"(a[3][0]), "+v"(a[3][1]), "+v"(a[3][2]), "+v"(a[3][3]));

  float rs[4][4];
  #pragma unroll
  for (int t = 0; t < 4; t++)
    #pragma unroll
    for (int r = 0; r < 4; r++) rs[t][r] = 0.0f;

  const char* bb = znP + ((size_t)tile0 << 12);   // 4 KB per tile

  short8 b[4];
  #pragma unroll
  for (int c = 0; c < 4; c++)
    b[c] = *(const short8*)(bb + (c << 10) + lane * 16);

  #pragma unroll 1
  for (int kt = 0; kt < NCT; kt++) {
    // prefetch next col-tile (coalesced; wraps on last iter — harmless)
    const int nkt = (kt + 1) & (NCT - 1);
    const char* bp = bb + ((size_t)nkt << 12);
    short8 bn[4];
    #pragma unroll
    for (int c = 0; c < 4; c++)
      bn[c] = *(const short8*)(bp + (c << 10) + lane * 16);

    #pragma unroll
    for (int t = 0; t < 4; t++) {
      float4v acc = {0.f, 0.f, 0.f, 0.f};
      acc = __builtin_amdgcn_mfma_f32_16x16x32_bf16(a[t][0], b[0], acc, 0, 0, 0);
      acc = __builtin_amdgcn_mfma_f32_16x16x32_bf16(a[t][1], b[1], acc, 0, 0, 0);
      acc = __builtin_amdgcn_mfma_f32_16x16x32_bf16(a[t][2], b[2], acc, 0, 0, 0);
      acc = __builtin_amdgcn_mfma_f32_16x16x32_bf16(a[t][3], b[3], acc, 0, 0, 0);
      // C/D: col = l15, row = quad*4 + r [m89/m91]; acc = 2log2e*sim.
      #pragma unroll
      for (int r = 0; r < 4; r++) rs[t][r] += EXP2F(acc[r]);
    }

    #pragma unroll
    for (int c = 0; c < 4; c++) b[c] = bn[c];
  }

  // reduce across the 16 lanes sharing each row, then one atomic each
  #pragma unroll
  for (int t = 0; t < 4; t++) {
    #pragma unroll
    for (int r = 0; r < 4; r++) {
      float s = rs[t][r];
      s += __shfl_xor(s, 1);
      s += __shfl_xor(s, 2);
      s += __shfl_xor(s, 4);
      s += __shfl_xor(s, 8);
      if (l15 == 0)
        atomicAdd(&rowsum[rowBase + t * 16 + quad * 4 + r], s);
    }
  }
}

// ---------------- Kernel 3: finalize --------------------------------------
__global__ __launch_bounds__(1024) void ntx_finalize_kernel(
    const float* __restrict__ rowsum, const float* __restrict__ pos,
    float* __restrict__ out) {
  float s = 0.f;
  for (int i = threadIdx.x; i < N2; i += 1024)
    s += __logf(rowsum[i]) - 2.0f * pos[i];
  #pragma unroll
  for (int o = 32; o > 0; o >>= 1) s += __shfl_xor(s, o);
  __shared__ float sm[16];
  const int wave = threadIdx.x >> 6;
  const int lane = threadIdx.x & 63;
  if (lane == 0) sm[wave] = s;
  __syncthreads();
  if (threadIdx.x == 0) {
    float t = 0.f;
    #pragma unroll
    for (int i = 0; i < 16; i++) t += sm[i];
    out[0] = t / (float)N2;
  }
}

extern "C" void kernel_launch(void* const* d_in, const int* in_sizes, int n_in,
                              void* d_out, int out_size, void* d_ws, size_t ws_size,
                              hipStream_t stream) {
  const float* zi = (const float*)d_in[0];
  const float* zj = (const float*)d_in[1];
  float* out = (float*)d_out;

  char* ws = (char*)d_ws;
  char* znP = ws;                                         // 2 MB packed frags
  float* rowsum = (float*)(ws + (size_t)N2 * DD * 2);     // 32 KB
  float* pos = rowsum + N2;                               // 32 KB

  ntx_norm_kernel<<<BB / 4, 256, 0, stream>>>(zi, zj, znP, rowsum, pos);
  dim3 grid(CSPLIT, N2 / 256);
  ntx_sim_kernel<<<grid, 256, 0, stream>>>(znP, rowsum);
  ntx_finalize_kernel<<<1, 1024, 0, stream>>>(rowsum, pos, out);
}